// Round 3
// baseline (696.219 us; speedup 1.0000x reference)
//
#include <hip/hip_runtime.h>
#include <math.h>

#define Bn 16
#define Ln 2048
#define Gn 8
#define Pn 8
#define Kn 64
#define CLAMP_V 15.0f

#define BPB 16              // blocks per batch -> grid = Bn*BPB = 256 blocks
#define NTH 1024            // threads per block = 16 waves
#define NWV (NTH / 64)      // 16 waves
#define LPB (Ln / BPB)      // 128 l's per block
#define LPW (LPB / NWV)     // 8 l's per wave

// d_ws layout: drms[Gn][Bn][Pn] floats, then cnt[Gn][Bn] ints.
// Both are written-once-per-slot (per call) and zeroed by init_ws.

__global__ __launch_bounds__(256) void init_ws(float* __restrict__ drms,
                                               int* __restrict__ cnt) {
    const int i = threadIdx.x;
    for (int j = i; j < Gn * Bn * Pn; j += 256) drms[j] = 0.0f;
    if (i < Gn * Bn) cnt[i] = 0;
}

// ---------------------------------------------------------------------------
// One kernel for the whole scan. Blocks never exit between groups; per-batch
// software barrier (16 blocks) via device-scope atomic counter. Each block
// keeps a PRIVATE full permutation table s_idx[Ln] in LDS and applies the
// (deterministic, redundant) per-group update locally, so only the 8 drms
// sums cross block boundaries.
// Co-residency: 256 blocks x 16 waves, <=128 VGPR (launch_bounds), 8.8KB LDS
// -> every CU can host 2 such blocks; 512 slots >= 256 blocks => all resident.
// ---------------------------------------------------------------------------
__global__ __launch_bounds__(NTH) void fused_kernel(
    const float* __restrict__ xpred, const float* __restrict__ xnat,
    const int* __restrict__ mask_in, const int* __restrict__ autom,
    float* __restrict__ out_x, float* __restrict__ out_m,
    float* __restrict__ drms, int* __restrict__ cnt) {

    const int tid  = threadIdx.x;
    const int lane = tid & 63;       // k
    const int wv   = tid >> 6;       // wave 0..15
    const int b    = blockIdx.x >> 4;
    const int c    = blockIdx.x & (BPB - 1);

    __shared__ int   s_idx[Ln];          // private permutation: xnat row map
    __shared__ float s_part[NWV][Pn];
    __shared__ float s_tot[Pn];
    __shared__ int   s_best;

    for (int l = tid; l < Ln; l += NTH) s_idx[l] = l;
    __syncthreads();

    const float* xpb = xpred + (size_t)b * Ln * 3;
    const float* xnb = xnat  + (size_t)b * Ln * 3;

    #pragma unroll 1
    for (int g = 0; g < Gn; g++) {
        const int* ag = autom + g * Pn * Kn;
        const int  gb = g * Bn + b;

        // ---- lane-k constants (read through current s_idx) ----
        const int a0k = ag[lane];
        const float px = xpb[a0k * 3 + 0];
        const float py = xpb[a0k * 3 + 1];
        const float pz = xpb[a0k * 3 + 2];

        float nx[Pn], ny[Pn], nz[Pn];
        #pragma unroll
        for (int p = 0; p < Pn; p++) {
            const int j = s_idx[ag[p * Kn + lane]];
            nx[p] = xnb[j * 3 + 0];
            ny[p] = xnb[j * 3 + 1];
            nz[p] = xnb[j * 3 + 2];
        }

        float acc[Pn];
        #pragma unroll
        for (int p = 0; p < Pn; p++) acc[p] = 0.0f;

        // ---- accumulate over this wave's l's ----
        const int l0 = c * LPB + wv * LPW;
        #pragma unroll
        for (int i = 0; i < LPW; i++) {
            const int l = l0 + i;
            if (__ballot(a0k == l)) continue;   // colmask: l in base set

            const int lu = __builtin_amdgcn_readfirstlane(l);
            const int ju = __builtin_amdgcn_readfirstlane(s_idx[l]);
            const float qx = xpb[lu * 3 + 0], qy = xpb[lu * 3 + 1], qz = xpb[lu * 3 + 2];
            const float mx = xnb[ju * 3 + 0], my = xnb[ju * 3 + 1], mz = xnb[ju * 3 + 2];

            const float dx = px - qx, dy = py - qy, dz = pz - qz;
            const float dp2 = dx * dx + dy * dy + dz * dz;

            #pragma unroll
            for (int p = 0; p < Pn; p++) {
                const float ex = nx[p] - mx, ey = ny[p] - my, ez = nz[p] - mz;
                const float dn2 = ex * ex + ey * ey + ez * ez;
                const float s  = __builtin_amdgcn_sqrtf(dp2 * dn2); // dp*dn, raw v_sqrt_f32
                const float t  = (dp2 + dn2) - 2.0f * s;            // (dp-dn)^2
                acc[p] += fminf(t, CLAMP_V);
            }
        }

        // ---- wave reduce (sum over k) ----
        #pragma unroll
        for (int p = 0; p < Pn; p++) {
            float v = acc[p];
            #pragma unroll
            for (int off = 32; off > 0; off >>= 1) v += __shfl_down(v, off, 64);
            if (lane == 0) s_part[wv][p] = v;
        }
        __syncthreads();

        // ---- block reduce: tid<128, p = tid>>4, w = tid&15 ----
        if (tid < NWV * Pn) {
            const int p = tid >> 4;
            float v = s_part[tid & 15][p];
            v += __shfl_down(v, 8, 16);
            v += __shfl_down(v, 4, 16);
            v += __shfl_down(v, 2, 16);
            v += __shfl_down(v, 1, 16);
            if ((tid & 15) == 0) atomicAdd(&drms[gb * Pn + p], v);  // device scope
        }
        __threadfence();
        __syncthreads();

        // ---- per-batch barrier: 16 blocks on cnt[gb] ----
        if (tid == 0) {
            __hip_atomic_fetch_add(&cnt[gb], 1, __ATOMIC_RELEASE, __HIP_MEMORY_SCOPE_AGENT);
            while (__hip_atomic_load(&cnt[gb], __ATOMIC_ACQUIRE, __HIP_MEMORY_SCOPE_AGENT) < BPB) {
                __builtin_amdgcn_s_sleep(1);
            }
        }
        __syncthreads();

        // ---- redundant argmin + private idx update ----
        if (tid < Pn)
            s_tot[tid] = __hip_atomic_load(&drms[gb * Pn + tid],
                                           __ATOMIC_RELAXED, __HIP_MEMORY_SCOPE_AGENT);
        __syncthreads();
        if (tid == 0) {
            float best = s_tot[0];
            int   bj   = 0;
            for (int p = 1; p < Pn; p++) {
                const float v = s_tot[p];
                if (v < best) { best = v; bj = p; }   // strict < == jnp.argmin tie rule
            }
            s_best = bj;
        }
        __syncthreads();

        const int bj = s_best;
        int oldv = 0;
        if (tid < Kn) oldv = s_idx[ag[bj * Kn + tid]];  // gather before scatter
        __syncthreads();
        if (tid < Kn) s_idx[ag[tid]] = oldv;
        __syncthreads();
    }

    // ---- epilogue: out = x_native[idx], mask[idx] ----
    const int l0 = c * LPB;
    if (tid < LPB * 3) {
        const int ll = tid / 3, coord = tid % 3;
        const int l  = l0 + ll;
        const int j  = s_idx[l];
        out_x[((size_t)b * Ln + l) * 3 + coord] = xnb[j * 3 + coord];
    } else if (tid < LPB * 4) {
        const int l = l0 + (tid - LPB * 3);
        const int j = s_idx[l];
        out_m[(size_t)b * Ln + l] = (float)mask_in[(size_t)b * Ln + j];
    }
}

// ---------------------------------------------------------------------------
extern "C" void kernel_launch(void* const* d_in, const int* in_sizes, int n_in,
                              void* d_out, int out_size, void* d_ws, size_t ws_size,
                              hipStream_t stream) {
    const float* xpred   = (const float*)d_in[0];  // (B,L,3) f32
    const float* xnat_in = (const float*)d_in[1];  // (B,L,3) f32
    const int*   mask_in = (const int*)  d_in[2];  // (B,L) bool -> int32
    const int*   autom   = (const int*)  d_in[3];  // (G,P,K) -> int32

    float* out_x = (float*)d_out;          // (B,L,3)
    float* out_m = out_x + Bn * Ln * 3;    // (B,L) as float 0/1

    float* drms = (float*)d_ws;                    // Gn*Bn*Pn floats
    int*   cnt  = (int*)(drms + Gn * Bn * Pn);     // Gn*Bn ints

    init_ws<<<1, 256, 0, stream>>>(drms, cnt);
    fused_kernel<<<Bn * BPB, NTH, 0, stream>>>(
        xpred, xnat_in, mask_in, autom, out_x, out_m, drms, cnt);
}

// Round 4
// 177.676 us; speedup vs baseline: 3.9185x; 3.9185x over previous
//
#include <hip/hip_runtime.h>
#include <math.h>

#define Bn 16
#define Ln 2048
#define Gn 8
#define Pn 8
#define Kn 64
#define CLAMP_V 15.0f

#define BPB 16              // blocks per batch -> grid = Bn*BPB = 256 blocks
#define NTH 1024            // threads per block = 16 waves
#define NWV (NTH / 64)      // 16 waves
#define LPB (Ln / BPB)      // 128 l's per block
#define LPW (LPB / NWV)     // 8 l's per wave

// d_ws layout: drms[Gn][Bn][Pn] floats, then cnt[Gn][Bn] ints (zeroed by init_ws;
// cross-kernel visibility of the zeros is guaranteed by the inter-dispatch flush).

__global__ __launch_bounds__(256) void init_ws(float* __restrict__ drms,
                                               int* __restrict__ cnt) {
    const int i = threadIdx.x;
    for (int j = i; j < Gn * Bn * Pn; j += 256) drms[j] = 0.0f;
    if (i < Gn * Bn) cnt[i] = 0;
}

__device__ __forceinline__ float bperm_f(int byte_addr, float v) {
    return __int_as_float(__builtin_amdgcn_ds_bpermute(byte_addr, __float_as_int(v)));
}

// ---------------------------------------------------------------------------
// Whole scan in one kernel. Per-batch 16-block barrier with RELAXED agent
// atomics ONLY — no __threadfence, no acquire/release (round-3's 75us/barrier
// came from buffer_wbl2/buffer_inv storms those fences emit). Ordering: the
// compiler drains vmcnt at __syncthreads, so drms atomicAdds are acked at the
// coherence point before tid0 bumps cnt; spinners' relaxed atomic loads bypass
// L1/L2 and read the coherence point directly.
// VALU cut: dn computed once per (base-point, l) — sqrts 8x amortized over the
// 8 perms; per-p value fetched cross-lane via ds_bpermute with a fixed sigma.
// ---------------------------------------------------------------------------
__global__ __launch_bounds__(NTH) void fused_kernel(
    const float* __restrict__ xpred, const float* __restrict__ xnat,
    const int* __restrict__ mask_in, const int* __restrict__ autom,
    float* __restrict__ out_x, float* __restrict__ out_m,
    float* __restrict__ drms, int* __restrict__ cnt) {

    const int tid  = threadIdx.x;
    const int lane = tid & 63;       // k / base-position j
    const int wv   = tid >> 6;       // wave 0..15
    const int b    = blockIdx.x >> 4;
    const int c    = blockIdx.x & (BPB - 1);

    __shared__ int            s_idx[Ln];       // private permutation: xnat row map
    __shared__ unsigned short s_inv[Ln];       // node id -> base position (this group)
    __shared__ float4         s_xp[LPB];       // x_pred columns for this block
    __shared__ float4         s_xn[LPB];       // x_nat_cur columns (re-gathered per group)
    __shared__ float          s_part[NWV][Pn];
    __shared__ float          s_tot[Pn];
    __shared__ int            s_best;

    for (int l = tid; l < Ln; l += NTH) s_idx[l] = l;
    if (tid < LPB) {
        const int l = c * LPB + tid;
        s_xp[tid] = make_float4(xpred[((size_t)b * Ln + l) * 3 + 0],
                                xpred[((size_t)b * Ln + l) * 3 + 1],
                                xpred[((size_t)b * Ln + l) * 3 + 2], 0.0f);
    }
    __syncthreads();

    const float* xpb = xpred + (size_t)b * Ln * 3;
    const float* xnb = xnat  + (size_t)b * Ln * 3;

    #pragma unroll 1
    for (int g = 0; g < Gn; g++) {
        const int* ag = autom + g * Pn * Kn;
        const int  gb = g * Bn + b;

        // ---- per-group LDS setup: inverse map + current x_nat columns ----
        if (tid < Kn) s_inv[ag[tid]] = (unsigned short)tid;
        if (tid < LPB) {
            const int j = s_idx[c * LPB + tid];
            s_xn[tid] = make_float4(xnb[j * 3 + 0], xnb[j * 3 + 1], xnb[j * 3 + 2], 0.0f);
        }
        __syncthreads();

        // ---- lane constants ----
        const int a0k = ag[lane];                 // base[lane]
        const float px = xpb[a0k * 3 + 0];
        const float py = xpb[a0k * 3 + 1];
        const float pz = xpb[a0k * 3 + 2];
        const int jn = s_idx[a0k];                // current row of base point
        const float nxx = xnb[jn * 3 + 0];
        const float nyy = xnb[jn * 3 + 1];
        const float nzz = xnb[jn * 3 + 2];

        int sig[Pn];                              // bpermute byte addresses
        #pragma unroll
        for (int p = 0; p < Pn; p++) sig[p] = 4 * (int)s_inv[ag[p * Kn + lane]];

        float acc[Pn];
        #pragma unroll
        for (int p = 0; p < Pn; p++) acc[p] = 0.0f;

        // ---- accumulate over this wave's l's ----
        const int il0 = wv * LPW;
        #pragma unroll
        for (int i = 0; i < LPW; i++) {
            const int il = il0 + i;
            const int l  = c * LPB + il;
            if (__ballot(a0k == l)) continue;     // colmask: l in base set

            const float4 q = s_xp[il];            // broadcast ds_read_b128
            const float4 m = s_xn[il];

            const float dx = px - q.x, dy = py - q.y, dz = pz - q.z;
            const float dp = __builtin_amdgcn_sqrtf(dx * dx + dy * dy + dz * dz);
            const float ex = nxx - m.x, ey = nyy - m.y, ez = nzz - m.z;
            const float dn = __builtin_amdgcn_sqrtf(ex * ex + ey * ey + ez * ez);

            #pragma unroll
            for (int p = 0; p < Pn; p++) {
                const float dns = bperm_f(sig[p], dn);   // dn at lane sigma_p(k)
                const float e   = dp - dns;
                acc[p] += fminf(e * e, CLAMP_V);
            }
        }

        // ---- wave reduce (sum over k) ----
        #pragma unroll
        for (int p = 0; p < Pn; p++) {
            float v = acc[p];
            #pragma unroll
            for (int off = 32; off > 0; off >>= 1) v += __shfl_down(v, off, 64);
            if (lane == 0) s_part[wv][p] = v;
        }
        __syncthreads();

        // ---- block reduce + one relaxed agent atomic per p ----
        if (tid < NWV * Pn) {
            const int p = tid >> 4;
            float v = s_part[tid & 15][p];
            v += __shfl_down(v, 8, 16);
            v += __shfl_down(v, 4, 16);
            v += __shfl_down(v, 2, 16);
            v += __shfl_down(v, 1, 16);
            if ((tid & 15) == 0)
                __hip_atomic_fetch_add(&drms[gb * Pn + p], v,
                                       __ATOMIC_RELAXED, __HIP_MEMORY_SCOPE_AGENT);
        }
        __syncthreads();   // drains vmcnt: adds acked before signal

        // ---- per-batch barrier: relaxed atomics only, no cache ops ----
        if (tid == 0) {
            __hip_atomic_fetch_add(&cnt[gb], 1, __ATOMIC_RELAXED, __HIP_MEMORY_SCOPE_AGENT);
            while (__hip_atomic_load(&cnt[gb], __ATOMIC_RELAXED, __HIP_MEMORY_SCOPE_AGENT) < BPB)
                __builtin_amdgcn_s_sleep(1);
        }
        __syncthreads();

        // ---- redundant argmin + private idx update ----
        if (tid < Pn)
            s_tot[tid] = __hip_atomic_load(&drms[gb * Pn + tid],
                                           __ATOMIC_RELAXED, __HIP_MEMORY_SCOPE_AGENT);
        __syncthreads();
        if (tid == 0) {
            float best = s_tot[0];
            int   bj   = 0;
            for (int p = 1; p < Pn; p++) {
                const float v = s_tot[p];
                if (v < best) { best = v; bj = p; }   // strict < == jnp.argmin tie rule
            }
            s_best = bj;
        }
        __syncthreads();

        const int bj = s_best;
        int oldv = 0;
        if (tid < Kn) oldv = s_idx[ag[bj * Kn + tid]];  // gather before scatter
        __syncthreads();
        if (tid < Kn) s_idx[ag[tid]] = oldv;
        __syncthreads();
    }

    // ---- epilogue: out = x_native[idx], mask[idx] ----
    const int l0 = c * LPB;
    if (tid < LPB * 3) {
        const int ll = tid / 3, coord = tid % 3;
        const int l  = l0 + ll;
        const int j  = s_idx[l];
        out_x[((size_t)b * Ln + l) * 3 + coord] = xnb[j * 3 + coord];
    } else if (tid < LPB * 4) {
        const int l = l0 + (tid - LPB * 3);
        const int j = s_idx[l];
        out_m[(size_t)b * Ln + l] = (float)mask_in[(size_t)b * Ln + j];
    }
}

// ---------------------------------------------------------------------------
extern "C" void kernel_launch(void* const* d_in, const int* in_sizes, int n_in,
                              void* d_out, int out_size, void* d_ws, size_t ws_size,
                              hipStream_t stream) {
    const float* xpred   = (const float*)d_in[0];  // (B,L,3) f32
    const float* xnat_in = (const float*)d_in[1];  // (B,L,3) f32
    const int*   mask_in = (const int*)  d_in[2];  // (B,L) bool -> int32
    const int*   autom   = (const int*)  d_in[3];  // (G,P,K) -> int32

    float* out_x = (float*)d_out;          // (B,L,3)
    float* out_m = out_x + Bn * Ln * 3;    // (B,L) as float 0/1

    float* drms = (float*)d_ws;                    // Gn*Bn*Pn floats
    int*   cnt  = (int*)(drms + Gn * Bn * Pn);     // Gn*Bn ints

    init_ws<<<1, 256, 0, stream>>>(drms, cnt);
    fused_kernel<<<Bn * BPB, NTH, 0, stream>>>(
        xpred, xnat_in, mask_in, autom, out_x, out_m, drms, cnt);
}